// Round 3
// baseline (801.114 us; speedup 1.0000x reference)
//
#include <hip/hip_runtime.h>
#include <cstdint>
#include <cstddef>

// Problem constants
#define DN 2048      // nodes
#define DB 16        // batch
#define DE 32768     // edges
#define FPAD 96      // F=66 padded to 96 (3 x K32 MFMA chunks)

typedef __bf16 bf16x8 __attribute__((ext_vector_type(8)));
typedef __bf16 bf16x4 __attribute__((ext_vector_type(4)));
typedef float f32x4 __attribute__((ext_vector_type(4)));

// ---------------------------------------------------------------------------
// prep: xcat1 = bf16[inputs | hx | 0pad], xcat2 = bf16[inputs | 0 (r*hx later) | 0pad],
//       wtru[o][k] = bf16 W_ru[k*3 + o/128][o%128], wtc[o][k] = bf16 W_c[k*3+o/64][o%64]
//       + zero cnt[2048] for the CSR count pass.
// ---------------------------------------------------------------------------
__global__ __launch_bounds__(256) void prep_kernel(
    const float* __restrict__ inputs, const float* __restrict__ hx,
    const float* __restrict__ Wru, const float* __restrict__ Wc,
    __bf16* __restrict__ xcat1, __bf16* __restrict__ xcat2,
    __bf16* __restrict__ wtru, __bf16* __restrict__ wtc,
    int* __restrict__ cnt) {
  int idx = blockIdx.x * 256 + threadIdx.x;
  const int T1 = DB * DN * FPAD;  // 3145728
  if (idx < 2 * T1) {
    int which = idx >= T1 ? 1 : 0;
    int i = idx - which * T1;
    int f = i % FPAD;
    int bn = i / FPAD;
    int n = bn & (DN - 1);
    int b = bn >> 11;
    __bf16 v = (__bf16)0.0f;
    if (f < 2) v = (__bf16)inputs[(b << 12) + n * 2 + f];
    else if (f < 66 && !which) v = (__bf16)hx[((size_t)b << 17) + (n << 6) + (f - 2)];
    if (which) xcat2[i] = v; else xcat1[i] = v;
  } else {
    int j = idx - 2 * T1;
    if (j < 384 * FPAD) {
      int k = j % FPAD, o = j / FPAD;
      wtru[j] = (k < 66) ? (__bf16)Wru[(k * 3 + (o >> 7)) * 128 + (o & 127)] : (__bf16)0.0f;
    } else {
      j -= 384 * FPAD;
      if (j < 192 * FPAD) {
        int k = j % FPAD, o = j / FPAD;
        wtc[j] = (k < 66) ? (__bf16)Wc[(k * 3 + (o >> 6)) * 64 + (o & 63)] : (__bf16)0.0f;
      } else {
        j -= 192 * FPAD;
        if (j < DN) cnt[j] = 0;
      }
    }
  }
}

// ---------------------------------------------------------------------------
// CSR build, parallel: count (one edge/thread) -> scan (1 block) -> scatter
// ---------------------------------------------------------------------------
__global__ __launch_bounds__(512) void csr_count(const int* __restrict__ rows,
                                                 int* __restrict__ cnt) {
  int e = blockIdx.x * 512 + threadIdx.x;
  atomicAdd(&cnt[rows[e]], 1);
}

__global__ __launch_bounds__(1024) void csr_scan(const int* __restrict__ cnt,
                                                 int* __restrict__ csr_ptr,
                                                 int* __restrict__ off) {
  __shared__ int sa[DN];
  __shared__ int sb[DN];
  int t = threadIdx.x;
  int c0 = cnt[t], c1 = cnt[t + 1024];
  sa[t] = c0; sa[t + 1024] = c1;
  __syncthreads();
  int* src = sa; int* dst = sb;
  for (int o = 1; o < DN; o <<= 1) {
    for (int i = t; i < DN; i += 1024) {
      int v = src[i];
      if (i >= o) v += src[i - o];
      dst[i] = v;
    }
    __syncthreads();
    int* tmp = src; src = dst; dst = tmp;
  }
  int e0 = src[t] - c0;          // exclusive
  int e1 = src[t + 1024] - c1;
  csr_ptr[t] = e0; csr_ptr[t + 1024] = e1;
  off[t] = e0; off[t + 1024] = e1;
  if (t == 0) csr_ptr[DN] = DE;
}

__global__ __launch_bounds__(512) void csr_scatter(
    const int* __restrict__ rows, const int* __restrict__ cols,
    const float* __restrict__ vals, int* __restrict__ off,
    int* __restrict__ csr_col, float* __restrict__ csr_val) {
  int e = blockIdx.x * 512 + threadIdx.x;
  int r = rows[e];
  int p = atomicAdd(&off[r], 1);
  csr_col[p] = cols[e];
  csr_val[p] = vals[e];
}

// ---------------------------------------------------------------------------
// small GEMM: Y[row, o'] = sum_k xcat[row,k] * WcatT[o'][k], row in [0,32768)
// Block 128x64, 4 waves (2x2), wave tile 64x32 (MT=4,NT=2), K=96 single stage.
// Col group g = o'/OD: g0 -> Y0 (f32), g1 -> y1b (bf16),
// g2 -> y2p in PACKED MFMA-B-fragment layout:
//   Y2[b][n][o] at ((((b*(OD/16) + (o>>4))*64 + (n>>5))*4 + ((n>>3)&3))*128
//                   + (o&15)*8 + (n&7))
// so adp_gemm's bv load is base + lane*16B (fully coalesced, 1KB/wave).
// The 4 r-values per (mt,nt) are j-contiguous -> one 8B store.
// This removes the separate transpose_y2 kernel entirely.
// ---------------------------------------------------------------------------
template <int OD>
__global__ __launch_bounds__(256) void small_gemm(
    const __bf16* __restrict__ A, const __bf16* __restrict__ Bt,
    float* __restrict__ Y0, __bf16* __restrict__ y1b, __bf16* __restrict__ y2p) {
  __shared__ __attribute__((aligned(16))) __bf16 As[128 * 104];
  __shared__ __attribute__((aligned(16))) __bf16 Bs[64 * 104];
  int tid = threadIdx.x;
  int wave = tid >> 6, lane = tid & 63;
  int lrow = lane & 15, quad = lane >> 4;
  int r0 = blockIdx.x * 128;
  int c0 = blockIdx.y * 64;
  const uint4* gA = (const uint4*)(A + (size_t)r0 * FPAD);
  const uint4* gB = (const uint4*)(Bt + (size_t)c0 * FPAD);
  uint4* sA = (uint4*)As;
  uint4* sB = (uint4*)Bs;
#pragma unroll
  for (int i = 0; i < 6; ++i) {  // 128*12 uint4
    int s = i * 256 + tid;
    int r = s / 12, c4 = s % 12;
    sA[r * 13 + c4] = gA[r * 12 + c4];
  }
#pragma unroll
  for (int i = 0; i < 3; ++i) {  // 64*12 uint4
    int s = i * 256 + tid;
    int r = s / 12, c4 = s % 12;
    sB[r * 13 + c4] = gB[r * 12 + c4];
  }
  __syncthreads();
  int wm = wave >> 1, wn = wave & 1;
  f32x4 acc[4][2];
#pragma unroll
  for (int mt = 0; mt < 4; ++mt)
#pragma unroll
    for (int nt = 0; nt < 2; ++nt) acc[mt][nt] = (f32x4){0.f, 0.f, 0.f, 0.f};
#pragma unroll
  for (int kk = 0; kk < 3; ++kk) {
    bf16x8 af[4], bv[2];
#pragma unroll
    for (int mt = 0; mt < 4; ++mt)
      af[mt] = *(const bf16x8*)(As + (wm * 64 + mt * 16 + lrow) * 104 + kk * 32 + quad * 8);
#pragma unroll
    for (int nt = 0; nt < 2; ++nt)
      bv[nt] = *(const bf16x8*)(Bs + (wn * 32 + nt * 16 + lrow) * 104 + kk * 32 + quad * 8);
#pragma unroll
    for (int mt = 0; mt < 4; ++mt)
#pragma unroll
      for (int nt = 0; nt < 2; ++nt)
        acc[mt][nt] = __builtin_amdgcn_mfma_f32_16x16x32_bf16(af[mt], bv[nt], acc[mt][nt], 0, 0, 0);
  }
#pragma unroll
  for (int mt = 0; mt < 4; ++mt)
#pragma unroll
    for (int nt = 0; nt < 2; ++nt) {
      int col = c0 + wn * 32 + nt * 16 + lrow;
      int g = col >> ((OD == 128) ? 7 : 6);
      int oo = col & (OD - 1);
      int rowb = r0 + wm * 64 + mt * 16 + quad * 4;  // + r
      if (g == 2) {
        int bb = rowb >> 11;          // batch (block never crosses 2048-boundary)
        int n_ = rowb & 2047;         // node index of r=0
        bf16x4 v;
#pragma unroll
        for (int r = 0; r < 4; ++r) v[r] = (__bf16)acc[mt][nt][r];
        size_t off = ((((size_t)bb * (OD / 16) + (oo >> 4)) * 64 + (n_ >> 5)) * 4 +
                      ((n_ >> 3) & 3)) * 128 + (oo & 15) * 8 + (n_ & 7);
        *(bf16x4*)(y2p + off) = v;
      } else {
#pragma unroll
        for (int r = 0; r < 4; ++r) {
          int row = rowb + r;
          float v = acc[mt][nt][r];
          size_t oi = (size_t)row * OD + oo;
          if (g == 0) Y0[oi] = v;
          else y1b[oi] = (__bf16)v;
        }
      }
    }
}

// ---------------------------------------------------------------------------
// pre = Y0 + S*Y1 (CSR gather), in place over Y0
// ---------------------------------------------------------------------------
template <int OD>
__global__ __launch_bounds__(256) void gather_pre(
    float* __restrict__ Y0, const __bf16* __restrict__ y1b,
    const int* __restrict__ csr_ptr, const int* __restrict__ csr_col,
    const float* __restrict__ csr_val) {
  constexpr int SH = (OD == 128) ? 7 : 6;
  int idx = blockIdx.x * 256 + threadIdx.x;  // B*N*OD total
  int o = idx & (OD - 1);
  int bn = idx >> SH;
  int n = bn & (DN - 1);
  int b = bn >> 11;
  float acc = Y0[idx];
  int e1 = csr_ptr[n + 1];
  const __bf16* yb = y1b + ((size_t)b << 11) * OD;
  for (int e = csr_ptr[n]; e < e1; ++e)
    acc += csr_val[e] * (float)yb[(size_t)csr_col[e] * OD + o];
  Y0[idx] = acc;
}

// ---------------------------------------------------------------------------
// adp GEMM + fused epilogue.  G[b,n,o] = sum_m adp[b,n,m]*Y2[b,m,o] + pre
//  IS_RU: s = sigmoid(G); o<64 -> xcat2[...,2+o] = bf16(s*hx); o>=64 -> u_buf = s
//  else : c = tanh(G); out = u*hx + (1-u)*c  -> d_out (f32)
//
// Round-7 structure (TLP + coalescing; no ILP games):
//  * R2 post-mortem: compiler SINKS register prefetches (VGPR stayed 56);
//    and per-lane y2t loads touched 16 lines each (row stride 4KB). Both
//    fixed here.
//  * BM=16, grid 2048 = 8 blocks/CU: latency hiding comes from 24-32
//    resident waves per CU (TLP), not from a software pipeline the
//    compiler won't keep.
//  * B is read from y2p, pre-packed in the exact MFMA B-fragment layout by
//    small_gemm: a bv load is base + lane*16B -> one contiguous 1KB line
//    set per wave-load instead of 16 lines.
//  * A (adp rows) read direct from global, f32->bf16 in-register; all 4
//    waves of a block read the SAME 16 A-rows -> 3/4 are L1 hits; each
//    HBM line fetched once.
//  * __launch_bounds__(256,6): cap ~85 VGPR -> no spills, >=6 blocks/CU.
// 4 waves, wave tile 16 x (OD/4): NT = OD/64 tiles of 16 cols.
// ---------------------------------------------------------------------------
template <int OD, bool IS_RU>
__global__ __launch_bounds__(256, 6) void adp_gemm(
    const float* __restrict__ adp, const __bf16* __restrict__ y2p,
    const float* __restrict__ pre, const float* __restrict__ hx,
    float* __restrict__ u_buf, __bf16* __restrict__ xcat2,
    float* __restrict__ outp) {
  constexpr int NT = OD / 64;        // 2 (ru) / 1 (c)
  int tid = threadIdx.x;
  int wave = tid >> 6, lane = tid & 63;
  int lrow = lane & 15, quad = lane >> 4;
  // XCD-aware swizzle: 2048 blocks, 8 XCDs -> 256 consecutive logical blocks
  // per XCD => 2 batches' y2p per XCD L2.
  int hw = blockIdx.x;
  int swz = (hw & 7) * 256 + (hw >> 3);
  int b = swz >> 7;                  // 128 row-blocks per batch
  int row0 = (swz & 127) * 16;
  const float* Ap = adp + ((size_t)b * DN + row0 + lrow) * DN + quad * 8;
  const __bf16* Bq[NT];
#pragma unroll
  for (int nt = 0; nt < NT; ++nt) {
    int ob = wave * NT + nt;
    Bq[nt] = y2p + ((size_t)b * (OD / 16) + ob) * (64 * 512) + lane * 8;
  }

  f32x4 acc[NT];
#pragma unroll
  for (int nt = 0; nt < NT; ++nt) acc[nt] = (f32x4){0.f, 0.f, 0.f, 0.f};

#pragma unroll 1
  for (int c = 0; c < DN / 64; ++c) {
    // B: packed fragments, fully coalesced (1KB per wave-load)
    bf16x8 bv[2][NT];
#pragma unroll
    for (int kk = 0; kk < 2; ++kk)
#pragma unroll
      for (int nt = 0; nt < NT; ++nt)
        bv[kk][nt] = *(const bf16x8*)(Bq[nt] + c * 1024 + kk * 512);
    // A: 16 rows x 256B per step; each line once (L1-shared across waves)
    const float* p_ = Ap + (size_t)c * 64;
    f32x4 a00 = *(const f32x4*)p_;
    f32x4 a01 = *(const f32x4*)(p_ + 4);
    f32x4 a10 = *(const f32x4*)(p_ + 32);
    f32x4 a11 = *(const f32x4*)(p_ + 36);
    bf16x8 af0, af1;
#pragma unroll
    for (int j = 0; j < 4; ++j) {
      af0[j] = (__bf16)a00[j]; af0[4 + j] = (__bf16)a01[j];
      af1[j] = (__bf16)a10[j]; af1[4 + j] = (__bf16)a11[j];
    }
#pragma unroll
    for (int nt = 0; nt < NT; ++nt)
      acc[nt] = __builtin_amdgcn_mfma_f32_16x16x32_bf16(af0, bv[0][nt], acc[nt], 0, 0, 0);
#pragma unroll
    for (int nt = 0; nt < NT; ++nt)
      acc[nt] = __builtin_amdgcn_mfma_f32_16x16x32_bf16(af1, bv[1][nt], acc[nt], 0, 0, 0);
  }

  // epilogue: C[m = quad*4+r][col = lrow]
#pragma unroll
  for (int nt = 0; nt < NT; ++nt)
#pragma unroll
    for (int r = 0; r < 4; ++r) {
      int n = row0 + quad * 4 + r;
      int o = wave * (NT * 16) + nt * 16 + lrow;
      float g = acc[nt][r] + pre[((size_t)b * DN + n) * OD + o];
      if (IS_RU) {
        float s = 1.f / (1.f + __expf(-g));
        if (o < 64) {  // r gate (wave-uniform: o<64 <=> wave<2)
          float hxv = hx[((size_t)b << 17) + n * 64 + o];
          xcat2[((size_t)b * DN + n) * FPAD + 2 + o] = (__bf16)(s * hxv);
        } else {       // u gate
          u_buf[((size_t)b * DN + n) * 64 + (o - 64)] = s;
        }
      } else {
        float cval = 1.f - 2.f / (__expf(2.f * g) + 1.f);  // tanh
        float u = u_buf[((size_t)b * DN + n) * 64 + o];
        float hxv = hx[((size_t)b << 17) + n * 64 + o];
        outp[((size_t)b << 17) + n * 64 + o] = u * hxv + (1.f - u) * cval;
      }
    }
}

// ---------------------------------------------------------------------------
extern "C" void kernel_launch(void* const* d_in, const int* in_sizes, int n_in,
                              void* d_out, int out_size, void* d_ws, size_t ws_size,
                              hipStream_t stream) {
  const float* inputs = (const float*)d_in[0];
  const float* hx     = (const float*)d_in[1];
  const float* adp    = (const float*)d_in[2];
  const int* srows    = (const int*)d_in[3];
  const int* scols    = (const int*)d_in[4];
  const float* svals  = (const float*)d_in[5];
  const float* Wru    = (const float*)d_in[6];
  const float* Wc     = (const float*)d_in[7];
  float* outp = (float*)d_out;

  char* w = (char*)d_ws;
  auto carve = [&](size_t bytes) -> char* {
    char* p = w;
    w += (bytes + 255) & ~(size_t)255;
    return p;
  };
  int*    csr_ptr = (int*)   carve((DN + 1) * sizeof(int));
  int*    csr_col = (int*)   carve(DE * sizeof(int));
  float*  csr_val = (float*) carve(DE * sizeof(float));
  int*    cnt     = (int*)   carve(DN * sizeof(int));
  int*    off     = (int*)   carve(DN * sizeof(int));
  __bf16* xcat1   = (__bf16*)carve((size_t)DB * DN * FPAD * 2);
  __bf16* xcat2   = (__bf16*)carve((size_t)DB * DN * FPAD * 2);
  __bf16* wtru    = (__bf16*)carve(384 * FPAD * 2);
  __bf16* wtc     = (__bf16*)carve(192 * FPAD * 2);
  float*  Y0      = (float*) carve((size_t)DB * DN * 128 * 4);  // doubles as `pre`
  __bf16* y1b     = (__bf16*)carve((size_t)DB * DN * 128 * 2);
  __bf16* y2b     = (__bf16*)carve((size_t)DB * DN * 128 * 2);  // (unused now)
  __bf16* y2p     = (__bf16*)carve((size_t)DB * DN * 128 * 2);  // packed B fragments
  float*  u_buf   = (float*) carve((size_t)DB * DN * 64 * 4);
  (void)ws_size; (void)in_sizes; (void)n_in; (void)out_size; (void)y2b;

  // 2*T1 (6291456) + 36864 + 18432 + 2048 = 6348800 = 24800 * 256
  prep_kernel<<<24800, 256, 0, stream>>>(inputs, hx, Wru, Wc, xcat1, xcat2,
                                         wtru, wtc, cnt);
  csr_count<<<64, 512, 0, stream>>>(srows, cnt);
  csr_scan<<<1, 1024, 0, stream>>>(cnt, csr_ptr, off);
  csr_scatter<<<64, 512, 0, stream>>>(srows, scols, svals, off, csr_col, csr_val);

  // ---- gconv 1 (r,u gates; OD = 128) ----
  small_gemm<128><<<dim3(256, 6), 256, 0, stream>>>(xcat1, wtru, Y0, y1b, y2p);
  gather_pre<128><<<16384, 256, 0, stream>>>(Y0, y1b, csr_ptr, csr_col, csr_val);
  adp_gemm<128, true><<<2048, 256, 0, stream>>>(
      adp, y2p, Y0, hx, u_buf, xcat2, outp);

  // ---- gconv 2 (candidate c; OD = 64) ----
  small_gemm<64><<<dim3(256, 3), 256, 0, stream>>>(xcat2, wtc, Y0, y1b, y2p);
  gather_pre<64><<<8192, 256, 0, stream>>>(Y0, y1b, csr_ptr, csr_col, csr_val);
  adp_gemm<64, false><<<2048, 256, 0, stream>>>(
      adp, y2p, Y0, hx, u_buf, xcat2, outp);
}

// Round 5
// 692.779 us; speedup vs baseline: 1.1564x; 1.1564x over previous
//
#include <hip/hip_runtime.h>
#include <cstdint>
#include <cstddef>

// Problem constants
#define DN 2048      // nodes
#define DB 16        // batch
#define DE 32768     // edges
#define FPAD 96      // F=66 padded to 96 (3 x K32 MFMA chunks)

typedef __bf16 bf16x8 __attribute__((ext_vector_type(8)));
typedef __bf16 bf16x4 __attribute__((ext_vector_type(4)));
typedef float f32x4 __attribute__((ext_vector_type(4)));

#define GLOAD16(src, dst)                                              \
  __builtin_amdgcn_global_load_lds(                                    \
      (const __attribute__((address_space(1))) void*)(src),            \
      (__attribute__((address_space(3))) void*)(dst), 16, 0, 0)

// ---------------------------------------------------------------------------
// prep: xcat1 = bf16[inputs | hx | 0pad], xcat2 = bf16[inputs | 0 (r*hx later) | 0pad],
//       wtru[o][k] = bf16 W_ru[k*3 + o/128][o%128], wtc[o][k] = bf16 W_c[k*3+o/64][o%64]
//       + zero cnt[2048] for the CSR count pass.
// ---------------------------------------------------------------------------
__global__ __launch_bounds__(256) void prep_kernel(
    const float* __restrict__ inputs, const float* __restrict__ hx,
    const float* __restrict__ Wru, const float* __restrict__ Wc,
    __bf16* __restrict__ xcat1, __bf16* __restrict__ xcat2,
    __bf16* __restrict__ wtru, __bf16* __restrict__ wtc,
    int* __restrict__ cnt) {
  int idx = blockIdx.x * 256 + threadIdx.x;
  const int T1 = DB * DN * FPAD;  // 3145728
  if (idx < 2 * T1) {
    int which = idx >= T1 ? 1 : 0;
    int i = idx - which * T1;
    int f = i % FPAD;
    int bn = i / FPAD;
    int n = bn & (DN - 1);
    int b = bn >> 11;
    __bf16 v = (__bf16)0.0f;
    if (f < 2) v = (__bf16)inputs[(b << 12) + n * 2 + f];
    else if (f < 66 && !which) v = (__bf16)hx[((size_t)b << 17) + (n << 6) + (f - 2)];
    if (which) xcat2[i] = v; else xcat1[i] = v;
  } else {
    int j = idx - 2 * T1;
    if (j < 384 * FPAD) {
      int k = j % FPAD, o = j / FPAD;
      wtru[j] = (k < 66) ? (__bf16)Wru[(k * 3 + (o >> 7)) * 128 + (o & 127)] : (__bf16)0.0f;
    } else {
      j -= 384 * FPAD;
      if (j < 192 * FPAD) {
        int k = j % FPAD, o = j / FPAD;
        wtc[j] = (k < 66) ? (__bf16)Wc[(k * 3 + (o >> 6)) * 64 + (o & 63)] : (__bf16)0.0f;
      } else {
        j -= 192 * FPAD;
        if (j < DN) cnt[j] = 0;
      }
    }
  }
}

// ---------------------------------------------------------------------------
// CSR build, parallel: count (one edge/thread) -> scan (1 block) -> scatter
// ---------------------------------------------------------------------------
__global__ __launch_bounds__(512) void csr_count(const int* __restrict__ rows,
                                                 int* __restrict__ cnt) {
  int e = blockIdx.x * 512 + threadIdx.x;
  atomicAdd(&cnt[rows[e]], 1);
}

__global__ __launch_bounds__(1024) void csr_scan(const int* __restrict__ cnt,
                                                 int* __restrict__ csr_ptr,
                                                 int* __restrict__ off) {
  __shared__ int sa[DN];
  __shared__ int sb[DN];
  int t = threadIdx.x;
  int c0 = cnt[t], c1 = cnt[t + 1024];
  sa[t] = c0; sa[t + 1024] = c1;
  __syncthreads();
  int* src = sa; int* dst = sb;
  for (int o = 1; o < DN; o <<= 1) {
    for (int i = t; i < DN; i += 1024) {
      int v = src[i];
      if (i >= o) v += src[i - o];
      dst[i] = v;
    }
    __syncthreads();
    int* tmp = src; src = dst; dst = tmp;
  }
  int e0 = src[t] - c0;          // exclusive
  int e1 = src[t + 1024] - c1;
  csr_ptr[t] = e0; csr_ptr[t + 1024] = e1;
  off[t] = e0; off[t + 1024] = e1;
  if (t == 0) csr_ptr[DN] = DE;
}

__global__ __launch_bounds__(512) void csr_scatter(
    const int* __restrict__ rows, const int* __restrict__ cols,
    const float* __restrict__ vals, int* __restrict__ off,
    int* __restrict__ csr_col, float* __restrict__ csr_val) {
  int e = blockIdx.x * 512 + threadIdx.x;
  int r = rows[e];
  int p = atomicAdd(&off[r], 1);
  csr_col[p] = cols[e];
  csr_val[p] = vals[e];
}

// ---------------------------------------------------------------------------
// small GEMM: Y[row, o'] = sum_k xcat[row,k] * WcatT[o'][k], row in [0,32768)
// Block 128x64, 4 waves (2x2), wave tile 64x32 (MT=4,NT=2), K=96 single stage.
// Col group g = o'/OD: g0 -> Y0 (f32), g1 -> y1b (bf16),
// g2 -> y2p in PACKED MFMA-B-fragment layout:
//   Y2[b][n][o] at ((((b*(OD/16) + (o>>4))*64 + (n>>5))*4 + ((n>>3)&3))*128
//                   + (o&15)*8 + (n&7))
// so adp_gemm's bv unit (o-block, k-tile, kk) is a contiguous 1KB run of
// lane*16B chunks -> both direct loads and global_load_lds stage linearly.
// ---------------------------------------------------------------------------
template <int OD>
__global__ __launch_bounds__(256) void small_gemm(
    const __bf16* __restrict__ A, const __bf16* __restrict__ Bt,
    float* __restrict__ Y0, __bf16* __restrict__ y1b, __bf16* __restrict__ y2p) {
  __shared__ __attribute__((aligned(16))) __bf16 As[128 * 104];
  __shared__ __attribute__((aligned(16))) __bf16 Bs[64 * 104];
  int tid = threadIdx.x;
  int wave = tid >> 6, lane = tid & 63;
  int lrow = lane & 15, quad = lane >> 4;
  int r0 = blockIdx.x * 128;
  int c0 = blockIdx.y * 64;
  const uint4* gA = (const uint4*)(A + (size_t)r0 * FPAD);
  const uint4* gB = (const uint4*)(Bt + (size_t)c0 * FPAD);
  uint4* sA = (uint4*)As;
  uint4* sB = (uint4*)Bs;
#pragma unroll
  for (int i = 0; i < 6; ++i) {  // 128*12 uint4
    int s = i * 256 + tid;
    int r = s / 12, c4 = s % 12;
    sA[r * 13 + c4] = gA[r * 12 + c4];
  }
#pragma unroll
  for (int i = 0; i < 3; ++i) {  // 64*12 uint4
    int s = i * 256 + tid;
    int r = s / 12, c4 = s % 12;
    sB[r * 13 + c4] = gB[r * 12 + c4];
  }
  __syncthreads();
  int wm = wave >> 1, wn = wave & 1;
  f32x4 acc[4][2];
#pragma unroll
  for (int mt = 0; mt < 4; ++mt)
#pragma unroll
    for (int nt = 0; nt < 2; ++nt) acc[mt][nt] = (f32x4){0.f, 0.f, 0.f, 0.f};
#pragma unroll
  for (int kk = 0; kk < 3; ++kk) {
    bf16x8 af[4], bv[2];
#pragma unroll
    for (int mt = 0; mt < 4; ++mt)
      af[mt] = *(const bf16x8*)(As + (wm * 64 + mt * 16 + lrow) * 104 + kk * 32 + quad * 8);
#pragma unroll
    for (int nt = 0; nt < 2; ++nt)
      bv[nt] = *(const bf16x8*)(Bs + (wn * 32 + nt * 16 + lrow) * 104 + kk * 32 + quad * 8);
#pragma unroll
    for (int mt = 0; mt < 4; ++mt)
#pragma unroll
      for (int nt = 0; nt < 2; ++nt)
        acc[mt][nt] = __builtin_amdgcn_mfma_f32_16x16x32_bf16(af[mt], bv[nt], acc[mt][nt], 0, 0, 0);
  }
#pragma unroll
  for (int mt = 0; mt < 4; ++mt)
#pragma unroll
    for (int nt = 0; nt < 2; ++nt) {
      int col = c0 + wn * 32 + nt * 16 + lrow;
      int g = col >> ((OD == 128) ? 7 : 6);
      int oo = col & (OD - 1);
      int rowb = r0 + wm * 64 + mt * 16 + quad * 4;  // + r
      if (g == 2) {
        int bb = rowb >> 11;          // batch (block never crosses 2048-boundary)
        int n_ = rowb & 2047;         // node index of r=0
        bf16x4 v;
#pragma unroll
        for (int r = 0; r < 4; ++r) v[r] = (__bf16)acc[mt][nt][r];
        size_t off = ((((size_t)bb * (OD / 16) + (oo >> 4)) * 64 + (n_ >> 5)) * 4 +
                      ((n_ >> 3) & 3)) * 128 + (oo & 15) * 8 + (n_ & 7);
        *(bf16x4*)(y2p + off) = v;
      } else {
#pragma unroll
        for (int r = 0; r < 4; ++r) {
          int row = rowb + r;
          float v = acc[mt][nt][r];
          size_t oi = (size_t)row * OD + oo;
          if (g == 0) Y0[oi] = v;
          else y1b[oi] = (__bf16)v;
        }
      }
    }
}

// ---------------------------------------------------------------------------
// pre = Y0 + S*Y1 (CSR gather), in place over Y0
// ---------------------------------------------------------------------------
template <int OD>
__global__ __launch_bounds__(256) void gather_pre(
    float* __restrict__ Y0, const __bf16* __restrict__ y1b,
    const int* __restrict__ csr_ptr, const int* __restrict__ csr_col,
    const float* __restrict__ csr_val) {
  constexpr int SH = (OD == 128) ? 7 : 6;
  int idx = blockIdx.x * 256 + threadIdx.x;  // B*N*OD total
  int o = idx & (OD - 1);
  int bn = idx >> SH;
  int n = bn & (DN - 1);
  int b = bn >> 11;
  float acc = Y0[idx];
  int e1 = csr_ptr[n + 1];
  const __bf16* yb = y1b + ((size_t)b << 11) * OD;
  for (int e = csr_ptr[n]; e < e1; ++e)
    acc += csr_val[e] * (float)yb[(size_t)csr_col[e] * OD + o];
  Y0[idx] = acc;
}

// ---------------------------------------------------------------------------
// adp GEMM + fused epilogue.  G[b,n,o] = sum_m adp[b,n,m]*Y2[b,m,o] + pre
//  IS_RU: s = sigmoid(G); o<64 -> xcat2[...,2+o] = bf16(s*hx); o>=64 -> u_buf = s
//  else : c = tanh(G); out = u*hx + (1-u)*c  -> d_out (f32)
//
// Round-9 structure: the HW-VERIFIED m195-m201 idiom (T3/T4):
//   global_load_lds staging + raw s_barrier + manual COUNTED vmcnt.
//  * R1-R3: compiler sinks register prefetches (plain HIP); R4: raw-asm
//    register loads crashed (alloc hazards). global_load_lds has NO dest
//    registers -> nothing to sink, nothing to misallocate; the m201
//    template proves counted vmcnt survives raw s_barrier.
//  * BM=32, BN=OD, K-step 64, double-buffered LDS (A 8KB f32 + B 16/8KB
//    bf16 per buffer). Per-iter: STAGE(c+1) -> vmcnt(6|4) [waits only for
//    stage(c), issued one full compute-phase ago] -> s_barrier -> ds_read
//    + cvt + 8|4 MFMA -> s_barrier.
//  * A LDS swizzle via PRE-SWIZZLED SOURCE (caveat #21): 32B chunk index
//    XOR (row&7); read applies same XOR -> af ds_read drops 16-way -> ~4-way.
//  * B staged straight from packed y2p (linear lane*16B) -> conflict-free.
//  * Grid 1024, XCD swizzle: 1 batch's y2p (512KB) per XCD L2.
// Waves 2x2: wave = 16 rows x OD/2 cols (MT=1, NT=OD/32).
// ---------------------------------------------------------------------------
template <int OD, bool IS_RU>
__global__ __launch_bounds__(256, 4) void adp_gemm(
    const float* __restrict__ adp, const __bf16* __restrict__ y2p,
    const float* __restrict__ pre, const float* __restrict__ hx,
    float* __restrict__ u_buf, __bf16* __restrict__ xcat2,
    float* __restrict__ outp) {
  constexpr int NT = OD / 32;          // per-wave o-tiles: 4 (ru) / 2 (c)
  constexpr int NB = OD / 32;          // B gload_lds per thread: 4 / 2
  constexpr int ABYTES = 32 * 256;     // 8KB  (32 rows x 64 f32)
  constexpr int BBYTES = OD * 128;     // 16KB / 8KB
  constexpr int BUFB = ABYTES + BBYTES;
  __shared__ __attribute__((aligned(16))) char smem[2 * BUFB];

  int tid = threadIdx.x;
  int wave = tid >> 6, lane = tid & 63;
  int lrow = lane & 15, quad = lane >> 4;
  int wm = wave >> 1, wn = wave & 1;
  // XCD-aware swizzle: 1024 blocks, 8 XCDs -> 128 consecutive logical
  // blocks (2 batches of rows... 128 blocks = 1 batch? 64 row-blocks/batch
  // -> 2 batches) per XCD.
  int hw = blockIdx.x;
  int swz = (hw & 7) * 128 + (hw >> 3);
  int b = swz >> 6;                    // 64 row-blocks per batch
  int row0 = (swz & 63) * 32;
  const float* Ab = adp + ((size_t)b * DN + row0) * DN;
  const __bf16* Bbase = y2p + (size_t)b * (OD / 16) * 32768;

  f32x4 acc[NT];
#pragma unroll
  for (int nt = 0; nt < NT; ++nt) acc[nt] = (f32x4){0.f, 0.f, 0.f, 0.f};

  int Rrow = wm * 16 + lrow;           // A row this lane consumes (0..31)

  auto STAGE = [&](int buf, int c) {
    char* base = smem + buf * BUFB;
    // A: 32 rows x 256B, source chunk-XOR pre-swizzled (caveat #21)
#pragma unroll
    for (int i = 0; i < 2; ++i) {
      int s = i * 256 + tid;
      int r = s >> 4, h = s & 15;
      int colf = ((((h >> 1) ^ (r & 7)) << 1) | (h & 1)) << 2;  // f32 col
      const float* src = Ab + (size_t)r * DN + c * 64 + colf;
      GLOAD16(src, base + s * 16);
    }
    // B: packed fragments, already lane-linear
#pragma unroll
    for (int i = 0; i < NB; ++i) {
      int s = i * 256 + tid;
      int ob = s >> 7, kk = (s >> 6) & 1, l = s & 63;
      const __bf16* src = Bbase + (size_t)ob * 32768 + c * 1024 + kk * 512 + l * 8;
      GLOAD16(src, base + ABYTES + s * 16);
    }
  };

  auto COMPUTE = [&](int buf) {
    const char* base = smem + buf * BUFB;
    bf16x8 af[2];
#pragma unroll
    for (int kk = 0; kk < 2; ++kk) {
      int chunk = (kk * 4 + quad) ^ (Rrow & 7);
      const f32x4* pa = (const f32x4*)(base + Rrow * 256 + chunk * 32);
      f32x4 a0 = pa[0], a1 = pa[1];
#pragma unroll
      for (int j = 0; j < 4; ++j) {
        af[kk][j] = (__bf16)a0[j];
        af[kk][4 + j] = (__bf16)a1[j];
      }
    }
#pragma unroll
    for (int kk = 0; kk < 2; ++kk)
#pragma unroll
      for (int nt = 0; nt < NT; ++nt) {
        int ob = wn * NT + nt;
        bf16x8 bv = *(const bf16x8*)(base + ABYTES + ob * 2048 + kk * 1024 + lane * 16);
        acc[nt] = __builtin_amdgcn_mfma_f32_16x16x32_bf16(af[kk], bv, acc[nt], 0, 0, 0);
      }
  };

  STAGE(0, 0);
#pragma unroll 1
  for (int c = 0; c < DN / 64 - 1; ++c) {
    STAGE((c + 1) & 1, c + 1);
    if constexpr (OD == 128) {
      asm volatile("s_waitcnt vmcnt(6)" ::: "memory");
    } else {
      asm volatile("s_waitcnt vmcnt(4)" ::: "memory");
    }
    __builtin_amdgcn_sched_barrier(0);
    __builtin_amdgcn_s_barrier();
    __builtin_amdgcn_sched_barrier(0);
    COMPUTE(c & 1);
    __builtin_amdgcn_s_barrier();
  }
  asm volatile("s_waitcnt vmcnt(0)" ::: "memory");
  __builtin_amdgcn_sched_barrier(0);
  __builtin_amdgcn_s_barrier();
  COMPUTE(1);                          // c = 31

  // epilogue: C[n = row0 + wm*16 + quad*4 + r][o = wn*(NT*16) + nt*16 + lrow]
#pragma unroll
  for (int nt = 0; nt < NT; ++nt)
#pragma unroll
    for (int r = 0; r < 4; ++r) {
      int n = row0 + wm * 16 + quad * 4 + r;
      int o = wn * (NT * 16) + nt * 16 + lrow;
      float g = acc[nt][r] + pre[((size_t)b * DN + n) * OD + o];
      if (IS_RU) {
        float s = 1.f / (1.f + __expf(-g));
        if (o < 64) {  // r gate (wave-uniform: o<64 <=> wn==0)
          float hxv = hx[((size_t)b << 17) + n * 64 + o];
          xcat2[((size_t)b * DN + n) * FPAD + 2 + o] = (__bf16)(s * hxv);
        } else {       // u gate
          u_buf[((size_t)b * DN + n) * 64 + (o - 64)] = s;
        }
      } else {
        float cval = 1.f - 2.f / (__expf(2.f * g) + 1.f);  // tanh
        float u = u_buf[((size_t)b * DN + n) * 64 + o];
        float hxv = hx[((size_t)b << 17) + n * 64 + o];
        outp[((size_t)b << 17) + n * 64 + o] = u * hxv + (1.f - u) * cval;
      }
    }
}

// ---------------------------------------------------------------------------
extern "C" void kernel_launch(void* const* d_in, const int* in_sizes, int n_in,
                              void* d_out, int out_size, void* d_ws, size_t ws_size,
                              hipStream_t stream) {
  const float* inputs = (const float*)d_in[0];
  const float* hx     = (const float*)d_in[1];
  const float* adp    = (const float*)d_in[2];
  const int* srows    = (const int*)d_in[3];
  const int* scols    = (const int*)d_in[4];
  const float* svals  = (const float*)d_in[5];
  const float* Wru    = (const float*)d_in[6];
  const float* Wc     = (const float*)d_in[7];
  float* outp = (float*)d_out;

  char* w = (char*)d_ws;
  auto carve = [&](size_t bytes) -> char* {
    char* p = w;
    w += (bytes + 255) & ~(size_t)255;
    return p;
  };
  int*    csr_ptr = (int*)   carve((DN + 1) * sizeof(int));
  int*    csr_col = (int*)   carve(DE * sizeof(int));
  float*  csr_val = (float*) carve(DE * sizeof(float));
  int*    cnt     = (int*)   carve(DN * sizeof(int));
  int*    off     = (int*)   carve(DN * sizeof(int));
  __bf16* xcat1   = (__bf16*)carve((size_t)DB * DN * FPAD * 2);
  __bf16* xcat2   = (__bf16*)carve((size_t)DB * DN * FPAD * 2);
  __bf16* wtru    = (__bf16*)carve(384 * FPAD * 2);
  __bf16* wtc     = (__bf16*)carve(192 * FPAD * 2);
  float*  Y0      = (float*) carve((size_t)DB * DN * 128 * 4);  // doubles as `pre`
  __bf16* y1b     = (__bf16*)carve((size_t)DB * DN * 128 * 2);
  __bf16* y2b     = (__bf16*)carve((size_t)DB * DN * 128 * 2);  // (unused now)
  __bf16* y2p     = (__bf16*)carve((size_t)DB * DN * 128 * 2);  // packed B fragments
  float*  u_buf   = (float*) carve((size_t)DB * DN * 64 * 4);
  (void)ws_size; (void)in_sizes; (void)n_in; (void)out_size; (void)y2b;

  // 2*T1 (6291456) + 36864 + 18432 + 2048 = 6348800 = 24800 * 256
  prep_kernel<<<24800, 256, 0, stream>>>(inputs, hx, Wru, Wc, xcat1, xcat2,
                                         wtru, wtc, cnt);
  csr_count<<<64, 512, 0, stream>>>(srows, cnt);
  csr_scan<<<1, 1024, 0, stream>>>(cnt, csr_ptr, off);
  csr_scatter<<<64, 512, 0, stream>>>(srows, scols, svals, off, csr_col, csr_val);

  // ---- gconv 1 (r,u gates; OD = 128) ----
  small_gemm<128><<<dim3(256, 6), 256, 0, stream>>>(xcat1, wtru, Y0, y1b, y2p);
  gather_pre<128><<<16384, 256, 0, stream>>>(Y0, y1b, csr_ptr, csr_col, csr_val);
  adp_gemm<128, true><<<1024, 256, 0, stream>>>(
      adp, y2p, Y0, hx, u_buf, xcat2, outp);

  // ---- gconv 2 (candidate c; OD = 64) ----
  small_gemm<64><<<dim3(256, 3), 256, 0, stream>>>(xcat2, wtc, Y0, y1b, y2p);
  gather_pre<64><<<8192, 256, 0, stream>>>(Y0, y1b, csr_ptr, csr_col, csr_val);
  adp_gemm<64, false><<<1024, 256, 0, stream>>>(
      adp, y2p, Y0, hx, u_buf, xcat2, outp);
}